// Round 3
// baseline (933.488 us; speedup 1.0000x reference)
//
#include <hip/hip_runtime.h>
#include <hip/hip_bf16.h>

// Problem constants
#define C_   32
#define S_   20
#define V_   8000     // 20^3
#define K3_  125
#define OC_  375      // 3*K3

// Workspace layout (float offsets)
#define WS_FLAGI 0                        // int flag in floats[0..3]
#define WS_ATTN1 16
#define WS_ATTN2 (WS_ATTN1 + 256000)
#define WS_OFFCH (WS_ATTN2 + 256000)      // + 150000*zc floats

static __device__ __forceinline__ float b2f(__hip_bfloat16 v) { return __bfloat162float(v); }

template<int ISB>
static __device__ __forceinline__ float ldin(const void* p, int i) {
    if (ISB) return b2f(((const __hip_bfloat16*)p)[i]);
    return ((const float*)p)[i];
}

// ---------------------------------------------------------------------------
// Dtype sniffer: packed-bf16 data has small-exponent bf16 in the LOW half of
// each 32-bit word; true fp32 has uniform mantissa bits there. 64-word vote.
// ---------------------------------------------------------------------------
__global__ void sniff_kernel(const unsigned* __restrict__ xw, int* __restrict__ flag)
{
    if (threadIdx.x == 0 && blockIdx.x == 0) {
        int votes = 0;
        for (int i = 0; i < 64; ++i) {
            unsigned lo = xw[i] & 0xFFFFu;
            unsigned e = (lo >> 7) & 0xFFu;
            if (e == 0u || (e >= 110u && e <= 140u)) votes++;
        }
        *flag = (votes >= 56) ? 1 : 0;   // 1 = bf16, 0 = fp32
    }
}

// ---------------------------------------------------------------------------
// Offset conv for z-planes [z0, z0+zc): dense 5^3 conv, 32 -> 375 ch, pad 2.
// Thread = 1 voxel x 5 output channels.
// ---------------------------------------------------------------------------
template<int ISB>
__global__ __launch_bounds__(256) void conv_off_kernel(
    const void* __restrict__ x,
    const void* __restrict__ w_off,
    const void* __restrict__ b_off,
    const int* __restrict__ flag,
    float* __restrict__ offch, int z0, int nv)
{
    if (*flag != ISB) return;
    int lv = blockIdx.x * 256 + threadIdx.x;   // local voxel in chunk
    int ob = blockIdx.y * 5;                   // output-channel base
    bool act = lv < nv;
    int lvc = act ? lv : 0;
    int z  = z0 + lvc / 400;
    int rm = lvc % 400;
    int yy = rm / 20, xx = rm % 20;

    float acc[5] = {0.f, 0.f, 0.f, 0.f, 0.f};
    for (int c = 0; c < C_; ++c) {
        int xbase = c * V_;
        int wbase = (ob * C_ + c) * K3_;
        #pragma unroll 1
        for (int kz = 0; kz < 5; ++kz) {
            int zi = z - 2 + kz;
            bool zv = (unsigned)zi < (unsigned)S_;
            int zcl = min(max(zi, 0), S_ - 1);
            #pragma unroll 1
            for (int ky = 0; ky < 5; ++ky) {
                int yi = yy - 2 + ky;
                bool yv = (unsigned)yi < (unsigned)S_;
                int ycl = min(max(yi, 0), S_ - 1);
                #pragma unroll
                for (int kx = 0; kx < 5; ++kx) {
                    int xi = xx - 2 + kx;
                    bool xv = (unsigned)xi < (unsigned)S_;
                    int xcl = min(max(xi, 0), S_ - 1);
                    float xval = ldin<ISB>(x, xbase + zcl * 400 + ycl * 20 + xcl);
                    xval = (zv && yv && xv) ? xval : 0.f;
                    int wo = wbase + kz * 25 + ky * 5 + kx;
                    #pragma unroll
                    for (int j = 0; j < 5; ++j)
                        acc[j] += ldin<ISB>(w_off, wo + j * C_ * K3_) * xval;
                }
            }
        }
    }
    if (act) {
        #pragma unroll
        for (int j = 0; j < 5; ++j)
            offch[(ob + j) * nv + lv] = acc[j] + ldin<ISB>(b_off, ob + j);
    }
}

// ---------------------------------------------------------------------------
// Deformable depthwise sample for z-planes [z0, z0+zc).
// Block = (plane-in-chunk, channel); x[c] staged in LDS as fp32 (32 KB).
// ---------------------------------------------------------------------------
template<int ISB>
__global__ __launch_bounds__(256) void deform_kernel(
    const void* __restrict__ x,
    const void* __restrict__ w_dw,
    const void* __restrict__ b_dw,
    const int* __restrict__ flag,
    const float* __restrict__ offch,
    float* __restrict__ attn1, int z0, int nv)
{
    if (*flag != ISB) return;
    __shared__ float xc[V_];
    int z = z0 + blockIdx.x;
    int c = blockIdx.y;
    int tid = threadIdx.x;
    for (int i = tid; i < V_; i += 256)
        xc[i] = ldin<ISB>(x, c * V_ + i);
    __syncthreads();

    float bdw = ldin<ISB>(b_dw, c);
    for (int vv = tid; vv < 400; vv += 256) {
        int lv = (z - z0) * 400 + vv;
        int y = vv / 20, xx = vv % 20;
        float acc = 0.f;
        #pragma unroll 1
        for (int k = 0; k < K3_; ++k) {
            int kz = k / 25, ky = (k / 5) % 5, kx = k % 5;
            float pd = (float)(z - 2 + kz) + offch[(3 * k + 0) * nv + lv];
            float ph = (float)(y - 2 + ky) + offch[(3 * k + 1) * nv + lv];
            float pw = (float)(xx - 2 + kx) + offch[(3 * k + 2) * nv + lv];
            float dof = floorf(pd), hof = floorf(ph), wof = floorf(pw);
            float fd = pd - dof, fh = ph - hof, fw = pw - wof;
            int id = (int)dof, ih = (int)hof, iw = (int)wof;
            float s = 0.f;
            #pragma unroll
            for (int dd = 0; dd < 2; ++dd) {
                int di = id + dd;
                bool dv = (unsigned)di < (unsigned)S_;
                int dc = min(max(di, 0), S_ - 1);
                float wd = dd ? fd : 1.f - fd;
                #pragma unroll
                for (int hh = 0; hh < 2; ++hh) {
                    int hi = ih + hh;
                    bool hv = (unsigned)hi < (unsigned)S_;
                    int hc = min(max(hi, 0), S_ - 1);
                    float wh = hh ? fh : 1.f - fh;
                    #pragma unroll
                    for (int ww2 = 0; ww2 < 2; ++ww2) {
                        int wi = iw + ww2;
                        bool wvv = (unsigned)wi < (unsigned)S_;
                        int wcl = min(max(wi, 0), S_ - 1);
                        float wwt = ww2 ? fw : 1.f - fw;
                        float val = (dv && hv && wvv) ? xc[dc * 400 + hc * 20 + wcl] : 0.f;
                        s += val * (wd * wh * wwt);
                    }
                }
            }
            acc += ldin<ISB>(w_dw, c * K3_ + k) * s;
        }
        attn1[c * V_ + z * 400 + vv] = acc + bdw;
    }
}

// ---------------------------------------------------------------------------
// Depthwise 7^3 conv, dilation 3, pad 9, per-tap bounds checks.
// ---------------------------------------------------------------------------
template<int ISB>
__global__ __launch_bounds__(256) void spatial_kernel(
    const void* __restrict__ w_sp,
    const void* __restrict__ b_sp,
    const int* __restrict__ flag,
    const float* __restrict__ attn1,
    float* __restrict__ attn2)
{
    if (*flag != ISB) return;
    int z = blockIdx.x;
    int c = blockIdx.y;
    int tid = threadIdx.x;
    const float* a = attn1 + c * V_;
    float bias = ldin<ISB>(b_sp, c);
    for (int vv = tid; vv < 400; vv += 256) {
        int y = vv / 20, xx = vv % 20;
        float acc = 0.f;
        #pragma unroll 1
        for (int kz = 0; kz < 7; ++kz) {
            int zi = z - 9 + 3 * kz;
            if ((unsigned)zi >= (unsigned)S_) continue;
            #pragma unroll 1
            for (int ky = 0; ky < 7; ++ky) {
                int yi = y - 9 + 3 * ky;
                if ((unsigned)yi >= (unsigned)S_) continue;
                #pragma unroll
                for (int kx = 0; kx < 7; ++kx) {
                    int xi = xx - 9 + 3 * kx;
                    bool v = (unsigned)xi < (unsigned)S_;
                    int xcl = min(max(xi, 0), S_ - 1);
                    float av = a[zi * 400 + yi * 20 + xcl];
                    acc += v ? ldin<ISB>(w_sp, c * 343 + kz * 49 + ky * 7 + kx) * av : 0.f;
                }
            }
        }
        attn2[c * V_ + z * 400 + vv] = acc + bias;
    }
}

// ---------------------------------------------------------------------------
// Pointwise 32x32 + bias, then gate: out = x * attn.
// ---------------------------------------------------------------------------
template<int ISB>
__global__ __launch_bounds__(256) void pw_kernel(
    const void* __restrict__ x,
    const void* __restrict__ w_pw,
    const void* __restrict__ b_pw,
    const int* __restrict__ flag,
    const float* __restrict__ attn2,
    void* __restrict__ out)
{
    if (*flag != ISB) return;
    int o = blockIdx.y;
    int v = blockIdx.x * 256 + threadIdx.x;
    if (v >= V_) return;
    float acc = ldin<ISB>(b_pw, o);
    #pragma unroll
    for (int cc = 0; cc < C_; ++cc)
        acc += ldin<ISB>(w_pw, o * C_ + cc) * attn2[cc * V_ + v];
    float r = ldin<ISB>(x, o * V_ + v) * acc;
    if (ISB) ((__hip_bfloat16*)out)[o * V_ + v] = __float2bfloat16(r);
    else     ((float*)out)[o * V_ + v] = r;
}

// ---------------------------------------------------------------------------
extern "C" void kernel_launch(void* const* d_in, const int* in_sizes, int n_in,
                              void* d_out, int out_size, void* d_ws, size_t ws_size,
                              hipStream_t stream)
{
    const void* x     = d_in[0];
    const void* w_off = d_in[1];
    const void* b_off = d_in[2];
    const void* w_dw  = d_in[3];
    const void* b_dw  = d_in[4];
    const void* w_sp  = d_in[5];
    const void* b_sp  = d_in[6];
    const void* w_pw  = d_in[7];
    const void* b_pw  = d_in[8];
    float* ws = (float*)d_ws;
    int* flag = (int*)d_ws;   // floats[0]

    // z-chunk size from available workspace (deterministic -> graph-safe).
    size_t favail = ws_size / 4;
    int zc = 1;
    const int cands[6] = {20, 10, 5, 4, 2, 1};
    for (int i = 0; i < 6; ++i) {
        if (favail >= (size_t)WS_OFFCH + (size_t)150000 * (size_t)cands[i]) { zc = cands[i]; break; }
    }

    hipLaunchKernelGGL(sniff_kernel, dim3(1), dim3(64), 0, stream,
                       (const unsigned*)x, flag);

    for (int z0 = 0; z0 < S_; z0 += zc) {
        int nv = 400 * zc;
        dim3 gc((nv + 255) / 256, 75);
        hipLaunchKernelGGL((conv_off_kernel<1>), gc, dim3(256), 0, stream,
                           x, w_off, b_off, flag, ws + WS_OFFCH, z0, nv);
        hipLaunchKernelGGL((conv_off_kernel<0>), gc, dim3(256), 0, stream,
                           x, w_off, b_off, flag, ws + WS_OFFCH, z0, nv);
        dim3 gd(zc, 32);
        hipLaunchKernelGGL((deform_kernel<1>), gd, dim3(256), 0, stream,
                           x, w_dw, b_dw, flag, ws + WS_OFFCH, ws + WS_ATTN1, z0, nv);
        hipLaunchKernelGGL((deform_kernel<0>), gd, dim3(256), 0, stream,
                           x, w_dw, b_dw, flag, ws + WS_OFFCH, ws + WS_ATTN1, z0, nv);
    }

    hipLaunchKernelGGL((spatial_kernel<1>), dim3(20, 32), dim3(256), 0, stream,
                       w_sp, b_sp, flag, ws + WS_ATTN1, ws + WS_ATTN2);
    hipLaunchKernelGGL((spatial_kernel<0>), dim3(20, 32), dim3(256), 0, stream,
                       w_sp, b_sp, flag, ws + WS_ATTN1, ws + WS_ATTN2);

    hipLaunchKernelGGL((pw_kernel<1>), dim3(32, 32), dim3(256), 0, stream,
                       x, w_pw, b_pw, flag, ws + WS_ATTN2, d_out);
    hipLaunchKernelGGL((pw_kernel<0>), dim3(32, 32), dim3(256), 0, stream,
                       x, w_pw, b_pw, flag, ws + WS_ATTN2, d_out);
}

// Round 4
// 389.449 us; speedup vs baseline: 2.3969x; 2.3969x over previous
//
#include <hip/hip_runtime.h>
#include <hip/hip_bf16.h>

// Problem constants
#define C_   32
#define S_   20
#define V_   8000     // 20^3
#define K3_  125
#define OC_  375      // 3*K3
#define NP_  384      // padded N
#define KK_  4000     // 32*125

// Workspace layout (float offsets). Total 2.78M floats = 11.12 MB.
#define WS_ATTN1 0
#define WS_ATTN2 256000
#define WS_OFFB  512000                    // bf16[375*8000] = 1.5M floats
#define WS_BPREP (WS_OFFB + 1500000)       // bf16[384*4000] = 768000 floats

typedef __attribute__((ext_vector_type(8))) short bf16x8;
typedef __attribute__((ext_vector_type(4))) float f32x4;

static __device__ __forceinline__ unsigned short f2bf(float f) {
    union { float f; unsigned u; } v; v.f = f;
    unsigned r = v.u + 0x7FFFu + ((v.u >> 16) & 1u);   // RTNE
    return (unsigned short)(r >> 16);
}
static __device__ __forceinline__ float bf2f(unsigned short b) {
    union { unsigned u; float f; } v; v.u = ((unsigned)b) << 16; return v.f;
}

// ---------------------------------------------------------------------------
// Weight transform: Bprep[n][k] bf16, k = tap*32 + c; n >= 375 zeroed.
// ---------------------------------------------------------------------------
__global__ __launch_bounds__(256) void prep_b_kernel(
    const float* __restrict__ w_off, unsigned short* __restrict__ Bprep)
{
    int idx = blockIdx.x * 256 + threadIdx.x;          // < 384*4000
    if (idx >= NP_ * KK_) return;
    int n = idx / KK_, r = idx % KK_;
    int tap = r >> 5, c = r & 31;
    float v = (n < OC_) ? w_off[n * KK_ + c * K3_ + tap] : 0.f;
    Bprep[idx] = f2bf(v);
}

// ---------------------------------------------------------------------------
// Offset conv as implicit-GEMM MFMA: D[M=8000][N=384] = A[M][K=4000]*B[K][N].
// Tile 64(M) x 128(N), 4 waves in 2x2, wave tile 32x64, mfma 16x16x32 bf16.
// K-chunk = one 5^3 tap (32 channels). Writes offb[n][m] bf16 (+bias).
// ---------------------------------------------------------------------------
__global__ __launch_bounds__(256) void gemm_off_kernel(
    const float* __restrict__ x,
    const unsigned short* __restrict__ Bprep,
    const float* __restrict__ b_off,
    unsigned short* __restrict__ offb)
{
    __shared__ unsigned short A_lds[64 * 40];    // pad 32->40: 2-way max on b128
    __shared__ unsigned short B_lds[128 * 40];

    const int t    = threadIdx.x;
    const int lane = t & 63;
    const int wave = t >> 6;
    const int wr   = wave >> 1;                  // M half (0/1)
    const int wc   = wave & 1;                   // N half (0/1)
    const int quad = lane >> 4;
    const int lrow = lane & 15;
    const int M0   = blockIdx.x * 64;
    const int N0   = blockIdx.y * 128;

    // A-staging coords (fixed per thread): m voxel + 8-channel group
    const int am = t & 63;
    const int cb = (t >> 6) * 8;
    const int mg = M0 + am;
    const int az = mg / 400, arm = mg % 400;
    const int ay = arm / 20, ax = arm % 20;

    // B-staging coords
    const int bn = t >> 1;
    const int bp = (t & 1) * 16;                 // k-offset within chunk (shorts)
    const unsigned short* bsrc_row = Bprep + (size_t)(N0 + bn) * KK_;

    f32x4 acc[2][4] = {};

    for (int tap = 0; tap < K3_; ++tap) {
        int kz = tap / 25, ky = (tap / 5) % 5, kx = tap % 5;
        // ---- stage A: x patch (64 m x 32 c) -> bf16 LDS
        int zi = az - 2 + kz, yi = ay - 2 + ky, xi = ax - 2 + kx;
        bool ok = ((unsigned)zi < (unsigned)S_) & ((unsigned)yi < (unsigned)S_)
                & ((unsigned)xi < (unsigned)S_);
        int px = ok ? (zi * 400 + yi * 20 + xi) : 0;
        const float* xs = x + cb * V_ + px;
        unsigned short hv[8];
        #pragma unroll
        for (int i = 0; i < 8; ++i) {
            float v = ok ? xs[i * V_] : 0.f;
            hv[i] = f2bf(v);
        }
        __syncthreads();   // previous iteration's LDS reads complete
        *(uint4*)&A_lds[am * 40 + cb] = *(const uint4*)hv;
        // ---- stage B: Bprep row slice (128 n x 32 k)
        const uint4* bsrc = (const uint4*)(bsrc_row + tap * 32 + bp);
        uint4 b0 = bsrc[0];
        uint4 b1 = bsrc[1];
        *(uint4*)&B_lds[bn * 40 + bp]     = b0;
        *(uint4*)&B_lds[bn * 40 + bp + 8] = b1;
        __syncthreads();
        // ---- MFMA
        bf16x8 af[2], bf[4];
        #pragma unroll
        for (int mi = 0; mi < 2; ++mi)
            af[mi] = *(const bf16x8*)&A_lds[(wr * 32 + mi * 16 + lrow) * 40 + quad * 8];
        #pragma unroll
        for (int ni = 0; ni < 4; ++ni)
            bf[ni] = *(const bf16x8*)&B_lds[(wc * 64 + ni * 16 + lrow) * 40 + quad * 8];
        #pragma unroll
        for (int mi = 0; mi < 2; ++mi)
            #pragma unroll
            for (int ni = 0; ni < 4; ++ni)
                acc[mi][ni] = __builtin_amdgcn_mfma_f32_16x16x32_bf16(
                    af[mi], bf[ni], acc[mi][ni], 0, 0, 0);
    }

    // ---- epilogue: D[row][col], row=quad*4+reg (M), col=lrow (N); +bias, bf16
    #pragma unroll
    for (int mi = 0; mi < 2; ++mi) {
        #pragma unroll
        for (int ni = 0; ni < 4; ++ni) {
            int col = wc * 64 + ni * 16 + lrow;
            int n = N0 + col;
            if (n < OC_) {
                float bias = b_off[n];
                #pragma unroll
                for (int r = 0; r < 4; ++r) {
                    int row = wr * 32 + mi * 16 + quad * 4 + r;
                    offb[(size_t)n * V_ + M0 + row] = f2bf(acc[mi][ni][r] + bias);
                }
            }
        }
    }
}

// ---------------------------------------------------------------------------
// Deformable depthwise sample. Block = (z-plane, channel); x[c] in LDS fp32.
// Offsets read as bf16 from offb[o][v].
// ---------------------------------------------------------------------------
__global__ __launch_bounds__(256) void deform_kernel(
    const float* __restrict__ x,
    const float* __restrict__ w_dw,
    const float* __restrict__ b_dw,
    const unsigned short* __restrict__ offb,
    float* __restrict__ attn1)
{
    __shared__ float xc[V_];
    int z = blockIdx.x;
    int c = blockIdx.y;
    int tid = threadIdx.x;
    for (int i = tid; i < V_; i += 256)
        xc[i] = x[c * V_ + i];
    __syncthreads();

    float bdw = b_dw[c];
    for (int vv = tid; vv < 400; vv += 256) {
        int v = z * 400 + vv;
        int y = vv / 20, xx = vv % 20;
        float acc = 0.f;
        #pragma unroll 1
        for (int k = 0; k < K3_; ++k) {
            int kz = k / 25, ky = (k / 5) % 5, kx = k % 5;
            float pd = (float)(z - 2 + kz) + bf2f(offb[(3 * k + 0) * V_ + v]);
            float ph = (float)(y - 2 + ky) + bf2f(offb[(3 * k + 1) * V_ + v]);
            float pw = (float)(xx - 2 + kx) + bf2f(offb[(3 * k + 2) * V_ + v]);
            float dof = floorf(pd), hof = floorf(ph), wof = floorf(pw);
            float fd = pd - dof, fh = ph - hof, fw = pw - wof;
            int id = (int)dof, ih = (int)hof, iw = (int)wof;
            float s = 0.f;
            #pragma unroll
            for (int dd = 0; dd < 2; ++dd) {
                int di = id + dd;
                bool dv = (unsigned)di < (unsigned)S_;
                int dc = min(max(di, 0), S_ - 1);
                float wd = dd ? fd : 1.f - fd;
                #pragma unroll
                for (int hh = 0; hh < 2; ++hh) {
                    int hi = ih + hh;
                    bool hv = (unsigned)hi < (unsigned)S_;
                    int hc = min(max(hi, 0), S_ - 1);
                    float wh = hh ? fh : 1.f - fh;
                    #pragma unroll
                    for (int ww2 = 0; ww2 < 2; ++ww2) {
                        int wi = iw + ww2;
                        bool wvv = (unsigned)wi < (unsigned)S_;
                        int wcl = min(max(wi, 0), S_ - 1);
                        float wwt = ww2 ? fw : 1.f - fw;
                        float val = (dv && hv && wvv) ? xc[dc * 400 + hc * 20 + wcl] : 0.f;
                        s += val * (wd * wh * wwt);
                    }
                }
            }
            acc += w_dw[c * K3_ + k] * s;
        }
        attn1[c * V_ + z * 400 + vv] = acc + bdw;
    }
}

// ---------------------------------------------------------------------------
// Depthwise 7^3 conv, dilation 3, pad 9, per-tap bounds checks.
// ---------------------------------------------------------------------------
__global__ __launch_bounds__(256) void spatial_kernel(
    const float* __restrict__ w_sp,
    const float* __restrict__ b_sp,
    const float* __restrict__ attn1,
    float* __restrict__ attn2)
{
    int z = blockIdx.x;
    int c = blockIdx.y;
    int tid = threadIdx.x;
    const float* a = attn1 + c * V_;
    float bias = b_sp[c];
    for (int vv = tid; vv < 400; vv += 256) {
        int y = vv / 20, xx = vv % 20;
        float acc = 0.f;
        #pragma unroll 1
        for (int kz = 0; kz < 7; ++kz) {
            int zi = z - 9 + 3 * kz;
            if ((unsigned)zi >= (unsigned)S_) continue;
            #pragma unroll 1
            for (int ky = 0; ky < 7; ++ky) {
                int yi = y - 9 + 3 * ky;
                if ((unsigned)yi >= (unsigned)S_) continue;
                #pragma unroll
                for (int kx = 0; kx < 7; ++kx) {
                    int xi = xx - 9 + 3 * kx;
                    bool v = (unsigned)xi < (unsigned)S_;
                    int xcl = min(max(xi, 0), S_ - 1);
                    float av = a[zi * 400 + yi * 20 + xcl];
                    acc += v ? w_sp[c * 343 + kz * 49 + ky * 7 + kx] * av : 0.f;
                }
            }
        }
        attn2[c * V_ + z * 400 + vv] = acc + bias;
    }
}

// ---------------------------------------------------------------------------
// Pointwise 32x32 + bias, then gate: out = x * attn.
// ---------------------------------------------------------------------------
__global__ __launch_bounds__(256) void pw_kernel(
    const float* __restrict__ x,
    const float* __restrict__ w_pw,
    const float* __restrict__ b_pw,
    const float* __restrict__ attn2,
    float* __restrict__ out)
{
    int o = blockIdx.y;
    int v = blockIdx.x * 256 + threadIdx.x;
    if (v >= V_) return;
    float acc = b_pw[o];
    #pragma unroll
    for (int cc = 0; cc < C_; ++cc)
        acc += w_pw[o * C_ + cc] * attn2[cc * V_ + v];
    out[o * V_ + v] = x[o * V_ + v] * acc;
}

// ---------------------------------------------------------------------------
extern "C" void kernel_launch(void* const* d_in, const int* in_sizes, int n_in,
                              void* d_out, int out_size, void* d_ws, size_t ws_size,
                              hipStream_t stream)
{
    const float* x     = (const float*)d_in[0];
    const float* w_off = (const float*)d_in[1];
    const float* b_off = (const float*)d_in[2];
    const float* w_dw  = (const float*)d_in[3];
    const float* b_dw  = (const float*)d_in[4];
    const float* w_sp  = (const float*)d_in[5];
    const float* b_sp  = (const float*)d_in[6];
    const float* w_pw  = (const float*)d_in[7];
    const float* b_pw  = (const float*)d_in[8];
    float* ws = (float*)d_ws;
    float* out = (float*)d_out;

    unsigned short* offb  = (unsigned short*)(ws + WS_OFFB);
    unsigned short* Bprep = (unsigned short*)(ws + WS_BPREP);

    hipLaunchKernelGGL(prep_b_kernel, dim3((NP_ * KK_ + 255) / 256), dim3(256), 0, stream,
                       w_off, Bprep);

    hipLaunchKernelGGL(gemm_off_kernel, dim3(125, 3), dim3(256), 0, stream,
                       x, Bprep, b_off, offb);

    hipLaunchKernelGGL(deform_kernel, dim3(20, 32), dim3(256), 0, stream,
                       x, w_dw, b_dw, offb, ws + WS_ATTN1);

    hipLaunchKernelGGL(spatial_kernel, dim3(20, 32), dim3(256), 0, stream,
                       w_sp, b_sp, ws + WS_ATTN1, ws + WS_ATTN2);

    hipLaunchKernelGGL(pw_kernel, dim3(32, 32), dim3(256), 0, stream,
                       x, w_pw, b_pw, ws + WS_ATTN2, out);
}

// Round 5
// 341.597 us; speedup vs baseline: 2.7327x; 1.1401x over previous
//
#include <hip/hip_runtime.h>
#include <hip/hip_bf16.h>

// Problem constants
#define C_   32
#define S_   20
#define V_   8000     // 20^3
#define K3_  125
#define OC_  375      // 3*K3
#define NP_  384      // padded N
#define KK_  4000     // 32*125

// Workspace layout (float offsets). Peak 2.668M floats = 10.67 MB.
#define WS_ATTN1T 0                        // fp32 [v][c]          256000
#define WS_XTB    256000                   // bf16 [v][c]          128000 fl
#define WS_WDWT   384000                   // fp32 [k][c]            4000
#define WS_WSPT   388000                   // fp32 [k][c]           10976
#define WS_WPWT   398976                   // fp32 [c][o]            1024
#define WS_OFFB   400000                   // bf16 [n][v]         1500000 fl
#define WS_BPREP  1900000                  // bf16 [n][k] 768000 fl; dead after
#define WS_ATTN2T 1900000                  //   gemm -> reused as fp32 [v][c]

typedef __attribute__((ext_vector_type(8))) short bf16x8;
typedef __attribute__((ext_vector_type(4))) float f32x4;

static __device__ __forceinline__ unsigned short f2bf(float f) {
    union { float f; unsigned u; } v; v.f = f;
    unsigned r = v.u + 0x7FFFu + ((v.u >> 16) & 1u);   // RTNE
    return (unsigned short)(r >> 16);
}
static __device__ __forceinline__ float bf2f(unsigned short b) {
    union { unsigned u; float f; } v; v.u = ((unsigned)b) << 16; return v.f;
}

// ---------------------------------------------------------------------------
// Transposes: xtb[v][c] bf16; wdwT[k][c]; wspT[k][c]; wpwT[c][o] (fp32).
// ---------------------------------------------------------------------------
__global__ __launch_bounds__(256) void transpose_kernel(
    const float* __restrict__ x,
    const float* __restrict__ w_dw,
    const float* __restrict__ w_sp,
    const float* __restrict__ w_pw,
    unsigned short* __restrict__ xtb,
    float* __restrict__ wdwT,
    float* __restrict__ wspT,
    float* __restrict__ wpwT)
{
    int i = blockIdx.x * 256 + threadIdx.x;
    if (i < 256000) {
        int v = i >> 5, c = i & 31;
        xtb[i] = f2bf(x[c * V_ + v]);
        return;
    }
    int j = i - 256000;
    if (j < 4000)  { wdwT[j] = w_dw[(j & 31) * K3_ + (j >> 5)]; return; }
    j -= 4000;
    if (j < 10976) { wspT[j] = w_sp[(j & 31) * 343 + (j >> 5)]; return; }
    j -= 10976;
    if (j < 1024)  { wpwT[j] = w_pw[(j & 31) * 32 + (j >> 5)]; return; }
}

// ---------------------------------------------------------------------------
// Weight transform: Bprep[n][k] bf16, k = tap*32 + c; n >= 375 zeroed.
// ---------------------------------------------------------------------------
__global__ __launch_bounds__(256) void prep_b_kernel(
    const float* __restrict__ w_off, unsigned short* __restrict__ Bprep)
{
    int idx = blockIdx.x * 256 + threadIdx.x;
    if (idx >= NP_ * KK_) return;
    int n = idx / KK_, r = idx % KK_;
    int tap = r >> 5, c = r & 31;
    float v = (n < OC_) ? w_off[n * KK_ + c * K3_ + tap] : 0.f;
    Bprep[idx] = f2bf(v);
}

// ---------------------------------------------------------------------------
// Offset conv as implicit-GEMM MFMA: D[8000][384] = A[8000][4000]*B[4000][384].
// Tile 64x64, grid (125,6), 4 waves 2x2, wave tile 32x32, mfma 16x16x32 bf16.
// A staged from xtb (1 dwordx4/thread/tap). Writes offb[n][m] bf16 (+bias).
// ---------------------------------------------------------------------------
__global__ __launch_bounds__(256) void gemm_off_kernel(
    const unsigned short* __restrict__ xtb,
    const unsigned short* __restrict__ Bprep,
    const float* __restrict__ b_off,
    unsigned short* __restrict__ offb)
{
    __shared__ unsigned short A_lds[64 * 40];
    __shared__ unsigned short B_lds[64 * 40];

    const int t    = threadIdx.x;
    const int lane = t & 63;
    const int wave = t >> 6;
    const int wr   = wave >> 1;
    const int wc   = wave & 1;
    const int quad = lane >> 4;
    const int lrow = lane & 15;
    const int M0   = blockIdx.x * 64;
    const int N0   = blockIdx.y * 64;

    // staging coords: row = t>>2, 8-short group = (t&3)*8
    const int srow = t >> 2;
    const int soff = (t & 3) * 8;
    const int mg = M0 + srow;
    const int az = mg / 400, arm = mg % 400;
    const int ay = arm / 20, ax = arm % 20;
    const unsigned short* brow = Bprep + (size_t)(N0 + srow) * KK_;

    f32x4 acc[2][2] = {};

    for (int tap = 0; tap < K3_; ++tap) {
        int kz = tap / 25, ky = (tap / 5) % 5, kx = tap % 5;
        int zi = az - 2 + kz, yi = ay - 2 + ky, xi = ax - 2 + kx;
        bool ok = ((unsigned)zi < (unsigned)S_) & ((unsigned)yi < (unsigned)S_)
                & ((unsigned)xi < (unsigned)S_);
        int px = ok ? (zi * 400 + yi * 20 + xi) : 0;
        uint4 a4 = *(const uint4*)(xtb + px * 32 + soff);
        if (!ok) a4 = make_uint4(0, 0, 0, 0);
        uint4 b4 = *(const uint4*)(brow + tap * 32 + soff);

        __syncthreads();
        *(uint4*)&A_lds[srow * 40 + soff] = a4;
        *(uint4*)&B_lds[srow * 40 + soff] = b4;
        __syncthreads();

        bf16x8 af[2], bf[2];
        #pragma unroll
        for (int mi = 0; mi < 2; ++mi)
            af[mi] = *(const bf16x8*)&A_lds[(wr * 32 + mi * 16 + lrow) * 40 + quad * 8];
        #pragma unroll
        for (int ni = 0; ni < 2; ++ni)
            bf[ni] = *(const bf16x8*)&B_lds[(wc * 32 + ni * 16 + lrow) * 40 + quad * 8];
        #pragma unroll
        for (int mi = 0; mi < 2; ++mi)
            #pragma unroll
            for (int ni = 0; ni < 2; ++ni)
                acc[mi][ni] = __builtin_amdgcn_mfma_f32_16x16x32_bf16(
                    af[mi], bf[ni], acc[mi][ni], 0, 0, 0);
    }

    #pragma unroll
    for (int mi = 0; mi < 2; ++mi) {
        #pragma unroll
        for (int ni = 0; ni < 2; ++ni) {
            int n = N0 + wc * 32 + ni * 16 + lrow;
            if (n < OC_) {
                float bias = b_off[n];
                #pragma unroll
                for (int r = 0; r < 4; ++r) {
                    int row = wr * 32 + mi * 16 + quad * 4 + r;
                    offb[(size_t)n * V_ + M0 + row] = f2bf(acc[mi][ni][r] + bias);
                }
            }
        }
    }
}

// ---------------------------------------------------------------------------
// Deformable depthwise sample, channel-last. Thread = (voxel, channel).
// Position math is lane-duplicated (free); all sample loads coalesced.
// ---------------------------------------------------------------------------
__global__ __launch_bounds__(256) void deform_kernel(
    const unsigned short* __restrict__ xtb,
    const float* __restrict__ wdwT,
    const float* __restrict__ b_dw,
    const unsigned short* __restrict__ offb,
    float* __restrict__ attn1T)
{
    int t = threadIdx.x;
    int c = t & 31;
    int v = blockIdx.x * 8 + (t >> 5);
    int z = v / 400, rm = v % 400;
    int y = rm / 20, xx = rm % 20;

    float acc = 0.f;
    #pragma unroll 1
    for (int kz = 0; kz < 5; ++kz) {
        #pragma unroll 1
        for (int ky = 0; ky < 5; ++ky) {
            #pragma unroll
            for (int kx = 0; kx < 5; ++kx) {
                int k = kz * 25 + ky * 5 + kx;
                float pd = (float)(z - 2 + kz) + bf2f(offb[(3 * k + 0) * V_ + v]);
                float ph = (float)(y - 2 + ky) + bf2f(offb[(3 * k + 1) * V_ + v]);
                float pw = (float)(xx - 2 + kx) + bf2f(offb[(3 * k + 2) * V_ + v]);
                float fd0 = floorf(pd), fh0 = floorf(ph), fw0 = floorf(pw);
                float fd = pd - fd0, fh = ph - fh0, fw = pw - fw0;
                int id = (int)fd0, ih = (int)fh0, iw = (int)fw0;
                int d0 = min(max(id, 0), S_ - 1),     d1 = min(max(id + 1, 0), S_ - 1);
                int h0 = min(max(ih, 0), S_ - 1),     h1 = min(max(ih + 1, 0), S_ - 1);
                int w0 = min(max(iw, 0), S_ - 1),     w1 = min(max(iw + 1, 0), S_ - 1);
                float wd0 = ((unsigned)id       < (unsigned)S_) ? 1.f - fd : 0.f;
                float wd1 = ((unsigned)(id + 1) < (unsigned)S_) ? fd       : 0.f;
                float wh0 = ((unsigned)ih       < (unsigned)S_) ? 1.f - fh : 0.f;
                float wh1 = ((unsigned)(ih + 1) < (unsigned)S_) ? fh       : 0.f;
                float ww0 = ((unsigned)iw       < (unsigned)S_) ? 1.f - fw : 0.f;
                float ww1 = ((unsigned)(iw + 1) < (unsigned)S_) ? fw       : 0.f;
                int r00 = d0 * 400 + h0 * 20, r01 = d0 * 400 + h1 * 20;
                int r10 = d1 * 400 + h0 * 20, r11 = d1 * 400 + h1 * 20;
                float s =
                    (bf2f(xtb[(r00 + w0) * 32 + c]) * ww0 +
                     bf2f(xtb[(r00 + w1) * 32 + c]) * ww1) * (wd0 * wh0) +
                    (bf2f(xtb[(r01 + w0) * 32 + c]) * ww0 +
                     bf2f(xtb[(r01 + w1) * 32 + c]) * ww1) * (wd0 * wh1) +
                    (bf2f(xtb[(r10 + w0) * 32 + c]) * ww0 +
                     bf2f(xtb[(r10 + w1) * 32 + c]) * ww1) * (wd1 * wh0) +
                    (bf2f(xtb[(r11 + w0) * 32 + c]) * ww0 +
                     bf2f(xtb[(r11 + w1) * 32 + c]) * ww1) * (wd1 * wh1);
                acc += wdwT[k * 32 + c] * s;
            }
        }
    }
    attn1T[v * 32 + c] = acc + b_dw[c];
}

// ---------------------------------------------------------------------------
// Depthwise 7^3 conv, dilation 3, pad 9, channel-last, coalesced.
// ---------------------------------------------------------------------------
__global__ __launch_bounds__(256) void spatial_kernel(
    const float* __restrict__ wspT,
    const float* __restrict__ b_sp,
    const float* __restrict__ attn1T,
    float* __restrict__ attn2T)
{
    int t = threadIdx.x;
    int c = t & 31;
    int v = blockIdx.x * 8 + (t >> 5);
    int z = v / 400, rm = v % 400;
    int y = rm / 20, xx = rm % 20;

    float acc = 0.f;
    #pragma unroll 1
    for (int kz = 0; kz < 7; ++kz) {
        int zi = z - 9 + 3 * kz;
        bool zv = (unsigned)zi < (unsigned)S_;
        int zc2 = min(max(zi, 0), S_ - 1);
        #pragma unroll 1
        for (int ky = 0; ky < 7; ++ky) {
            int yi = y - 9 + 3 * ky;
            bool yv = (unsigned)yi < (unsigned)S_;
            int yc2 = min(max(yi, 0), S_ - 1);
            int abase = (zc2 * 400 + yc2 * 20) * 32 + c;
            int wbase = (kz * 49 + ky * 7) * 32 + c;
            #pragma unroll
            for (int kx = 0; kx < 7; ++kx) {
                int xi = xx - 9 + 3 * kx;
                bool xv = (unsigned)xi < (unsigned)S_;
                int xc2 = min(max(xi, 0), S_ - 1);
                float a = attn1T[abase + xc2 * 32];
                float w = wspT[wbase + kx * 32];
                acc += (zv && yv && xv) ? a * w : 0.f;
            }
        }
    }
    attn2T[v * 32 + c] = acc + b_sp[c];
}

// ---------------------------------------------------------------------------
// Pointwise 32x32 + bias, gate: out[o][v] = x[o][v] * attn.
// ---------------------------------------------------------------------------
__global__ __launch_bounds__(256) void pw_kernel(
    const float* __restrict__ x,
    const float* __restrict__ wpwT,
    const float* __restrict__ b_pw,
    const float* __restrict__ attn2T,
    float* __restrict__ out)
{
    int t = threadIdx.x;
    int o = t & 31;
    int v = blockIdx.x * 8 + (t >> 5);
    float acc = b_pw[o];
    #pragma unroll
    for (int c = 0; c < C_; ++c)
        acc += wpwT[c * 32 + o] * attn2T[v * 32 + c];
    out[o * V_ + v] = x[o * V_ + v] * acc;
}

// ---------------------------------------------------------------------------
extern "C" void kernel_launch(void* const* d_in, const int* in_sizes, int n_in,
                              void* d_out, int out_size, void* d_ws, size_t ws_size,
                              hipStream_t stream)
{
    const float* x     = (const float*)d_in[0];
    const float* w_off = (const float*)d_in[1];
    const float* b_off = (const float*)d_in[2];
    const float* w_dw  = (const float*)d_in[3];
    const float* b_dw  = (const float*)d_in[4];
    const float* w_sp  = (const float*)d_in[5];
    const float* b_sp  = (const float*)d_in[6];
    const float* w_pw  = (const float*)d_in[7];
    const float* b_pw  = (const float*)d_in[8];
    float* ws = (float*)d_ws;
    float* out = (float*)d_out;

    unsigned short* xtb   = (unsigned short*)(ws + WS_XTB);
    unsigned short* offb  = (unsigned short*)(ws + WS_OFFB);
    unsigned short* Bprep = (unsigned short*)(ws + WS_BPREP);

    hipLaunchKernelGGL(transpose_kernel, dim3((272000 + 255) / 256), dim3(256), 0, stream,
                       x, w_dw, w_sp, w_pw, xtb,
                       ws + WS_WDWT, ws + WS_WSPT, ws + WS_WPWT);

    hipLaunchKernelGGL(prep_b_kernel, dim3((NP_ * KK_ + 255) / 256), dim3(256), 0, stream,
                       w_off, Bprep);

    hipLaunchKernelGGL(gemm_off_kernel, dim3(125, 6), dim3(256), 0, stream,
                       xtb, Bprep, b_off, offb);

    hipLaunchKernelGGL(deform_kernel, dim3(1000), dim3(256), 0, stream,
                       xtb, ws + WS_WDWT, b_dw, offb, ws + WS_ATTN1T);

    hipLaunchKernelGGL(spatial_kernel, dim3(1000), dim3(256), 0, stream,
                       ws + WS_WSPT, b_sp, ws + WS_ATTN1T, ws + WS_ATTN2T);

    hipLaunchKernelGGL(pw_kernel, dim3(1000), dim3(256), 0, stream,
                       x, ws + WS_WPWT, b_pw, ws + WS_ATTN2T, out);
}

// Round 6
// 226.297 us; speedup vs baseline: 4.1251x; 1.5095x over previous
//
#include <hip/hip_runtime.h>
#include <hip/hip_bf16.h>

// Problem constants
#define C_   32
#define S_   20
#define V_   8000     // 20^3
#define K3_  125
#define OC_  375      // 3*K3
#define NP_  384      // padded N
#define KK_  4000     // 32*125

// Workspace layout (float offsets). Peak 2.704M floats = 10.82 MB.
#define WS_ATTN1T 0                        // fp32 [v][c]          256000
#define WS_XTB    256000                   // bf16 [v][c]          128000 fl
#define WS_WDWT   384000                   // fp32 [k][c]            4000
#define WS_WSPT   388000                   // fp32 [k][c]           10976
#define WS_WPWT   398976                   // fp32 [c][o]            1024
#define WS_OFFB   400000                   // bf16 [v][384]       1536000 fl
#define WS_BPREP  1936000                  // bf16 [n][k] 768000 fl; dead after
#define WS_ATTN2T 1936000                  //   gemm -> reused as fp32 [v][c]

typedef __attribute__((ext_vector_type(8))) short bf16x8;
typedef __attribute__((ext_vector_type(4))) float f32x4;

static __device__ __forceinline__ unsigned short f2bf(float f) {
    union { float f; unsigned u; } v; v.f = f;
    unsigned r = v.u + 0x7FFFu + ((v.u >> 16) & 1u);   // RTNE
    return (unsigned short)(r >> 16);
}
static __device__ __forceinline__ float bf2f(unsigned short b) {
    union { unsigned u; float f; } v; v.u = ((unsigned)b) << 16; return v.f;
}
static __device__ __forceinline__ float asf(unsigned u) {
    union { unsigned u; float f; } v; v.u = u; return v.f;
}

// ---------------------------------------------------------------------------
// Transposes: xtb[v][c] bf16; wdwT[k][c]; wspT[k][c]; wpwT[c][o] (fp32).
// ---------------------------------------------------------------------------
__global__ __launch_bounds__(256) void transpose_kernel(
    const float* __restrict__ x,
    const float* __restrict__ w_dw,
    const float* __restrict__ w_sp,
    const float* __restrict__ w_pw,
    unsigned short* __restrict__ xtb,
    float* __restrict__ wdwT,
    float* __restrict__ wspT,
    float* __restrict__ wpwT)
{
    int i = blockIdx.x * 256 + threadIdx.x;
    if (i < 256000) {
        int v = i >> 5, c = i & 31;
        xtb[i] = f2bf(x[c * V_ + v]);
        return;
    }
    int j = i - 256000;
    if (j < 4000)  { wdwT[j] = w_dw[(j & 31) * K3_ + (j >> 5)]; return; }
    j -= 4000;
    if (j < 10976) { wspT[j] = w_sp[(j & 31) * 343 + (j >> 5)]; return; }
    j -= 10976;
    if (j < 1024)  { wpwT[j] = w_pw[(j & 31) * 32 + (j >> 5)]; return; }
}

// ---------------------------------------------------------------------------
// Weight transform: Bprep[n][k] bf16, k = tap*32 + c; n >= 375 zeroed.
// ---------------------------------------------------------------------------
__global__ __launch_bounds__(256) void prep_b_kernel(
    const float* __restrict__ w_off, unsigned short* __restrict__ Bprep)
{
    int idx = blockIdx.x * 256 + threadIdx.x;
    if (idx >= NP_ * KK_) return;
    int n = idx / KK_, r = idx % KK_;
    int tap = r >> 5, c = r & 31;
    float v = (n < OC_) ? w_off[n * KK_ + c * K3_ + tap] : 0.f;
    Bprep[idx] = f2bf(v);
}

// ---------------------------------------------------------------------------
// Offset conv as implicit-GEMM MFMA: D[8000][384] = A[8000][4000]*B[4000][384].
// Tile 64x64, BK=64 (2 taps/iter, tap-parity LDS banks), 4 waves 2x2,
// wave tile 32x32, mfma 16x16x32 bf16. Writes offbT[v][n] bf16 (+bias).
// ---------------------------------------------------------------------------
__global__ __launch_bounds__(256) void gemm_off_kernel(
    const unsigned short* __restrict__ xtb,
    const unsigned short* __restrict__ Bprep,
    const float* __restrict__ b_off,
    unsigned short* __restrict__ offbT)
{
    __shared__ unsigned short A_lds[2][64 * 40];
    __shared__ unsigned short B_lds[2][64 * 40];

    const int t    = threadIdx.x;
    const int lane = t & 63;
    const int wave = t >> 6;
    const int wr   = wave >> 1;
    const int wc   = wave & 1;
    const int quad = lane >> 4;
    const int lrow = lane & 15;
    const int M0   = blockIdx.x * 64;
    const int N0   = blockIdx.y * 64;

    const int srow = t >> 2;
    const int soff = (t & 3) * 8;
    const int mg = M0 + srow;
    const int az = mg / 400, arm = mg % 400;
    const int ay = arm / 20, ax = arm % 20;
    const unsigned short* brow = Bprep + (size_t)(N0 + srow) * KK_;

    f32x4 acc[2][2] = {};

    for (int tap0 = 0; tap0 < 126; tap0 += 2) {
        uint4 a4[2], b4[2];
        #pragma unroll
        for (int h = 0; h < 2; ++h) {
            int tap = tap0 + h;
            int kz = tap / 25, ky = (tap / 5) % 5, kx = tap % 5;
            int zi = az - 2 + kz, yi = ay - 2 + ky, xi = ax - 2 + kx;
            bool intap = tap < K3_;
            bool ok = intap & ((unsigned)zi < (unsigned)S_)
                            & ((unsigned)yi < (unsigned)S_)
                            & ((unsigned)xi < (unsigned)S_);
            int px = ok ? (zi * 400 + yi * 20 + xi) : 0;
            a4[h] = *(const uint4*)(xtb + px * 32 + soff);
            if (!ok) a4[h] = make_uint4(0, 0, 0, 0);
            b4[h] = *(const uint4*)(brow + (intap ? tap : 0) * 32 + soff);
            if (!intap) b4[h] = make_uint4(0, 0, 0, 0);
        }
        __syncthreads();
        *(uint4*)&A_lds[0][srow * 40 + soff] = a4[0];
        *(uint4*)&A_lds[1][srow * 40 + soff] = a4[1];
        *(uint4*)&B_lds[0][srow * 40 + soff] = b4[0];
        *(uint4*)&B_lds[1][srow * 40 + soff] = b4[1];
        __syncthreads();
        #pragma unroll
        for (int h = 0; h < 2; ++h) {
            bf16x8 af[2], bf[2];
            #pragma unroll
            for (int mi = 0; mi < 2; ++mi)
                af[mi] = *(const bf16x8*)&A_lds[h][(wr * 32 + mi * 16 + lrow) * 40 + quad * 8];
            #pragma unroll
            for (int ni = 0; ni < 2; ++ni)
                bf[ni] = *(const bf16x8*)&B_lds[h][(wc * 32 + ni * 16 + lrow) * 40 + quad * 8];
            #pragma unroll
            for (int mi = 0; mi < 2; ++mi)
                #pragma unroll
                for (int ni = 0; ni < 2; ++ni)
                    acc[mi][ni] = __builtin_amdgcn_mfma_f32_16x16x32_bf16(
                        af[mi], bf[ni], acc[mi][ni], 0, 0, 0);
        }
    }

    #pragma unroll
    for (int mi = 0; mi < 2; ++mi) {
        #pragma unroll
        for (int ni = 0; ni < 2; ++ni) {
            int n = N0 + wc * 32 + ni * 16 + lrow;
            if (n < OC_) {
                float bias = b_off[n];
                #pragma unroll
                for (int r = 0; r < 4; ++r) {
                    int row = wr * 32 + mi * 16 + quad * 4 + r;
                    offbT[(size_t)(M0 + row) * 384 + n] = f2bf(acc[mi][ni][r] + bias);
                }
            }
        }
    }
}

// ---------------------------------------------------------------------------
// Deformable depthwise sample, two-phase.
// Phase 1: per (voxel, tap) geometry computed ONCE -> 24B in LDS.
// Phase 2: thread=(v,c); 3 broadcast LDS dwords + 8 coalesced gathers + FMAs.
// ---------------------------------------------------------------------------
#define VB 8
__global__ __launch_bounds__(256) void deform_kernel(
    const unsigned short* __restrict__ xtb,
    const float* __restrict__ wdwT,
    const float* __restrict__ b_dw,
    const unsigned short* __restrict__ offbT,
    float* __restrict__ attn1T)
{
    __shared__ unsigned short sw[VB * 128 * 12];   // 24 KB
    const int tid = threadIdx.x;
    const int Vb = blockIdx.x * VB;

    for (int idx = tid; idx < VB * 128; idx += 256) {
        int vl = idx >> 7, tap = idx & 127;
        if (tap < K3_) {
            int v = Vb + vl;
            int z = v / 400, rm = v % 400;
            int y = rm / 20, xx = rm % 20;
            int kz = tap / 25, ky = (tap / 5) % 5, kx = tap % 5;
            const unsigned short* ob = offbT + v * 384 + 3 * tap;
            float pd = (float)(z - 2 + kz) + bf2f(ob[0]);
            float ph = (float)(y - 2 + ky) + bf2f(ob[1]);
            float pw = (float)(xx - 2 + kx) + bf2f(ob[2]);
            float fd0 = floorf(pd), fh0 = floorf(ph), fw0 = floorf(pw);
            float fd = pd - fd0, fh = ph - fh0, fw = pw - fw0;
            int id = (int)fd0, ih = (int)fh0, iw = (int)fw0;
            int d0 = min(max(id, 0), S_ - 1), d1 = min(max(id + 1, 0), S_ - 1);
            int h0 = min(max(ih, 0), S_ - 1), h1 = min(max(ih + 1, 0), S_ - 1);
            int w0 = min(max(iw, 0), S_ - 1), w1 = min(max(iw + 1, 0), S_ - 1);
            float wd0 = ((unsigned)id       < (unsigned)S_) ? 1.f - fd : 0.f;
            float wd1 = ((unsigned)(id + 1) < (unsigned)S_) ? fd       : 0.f;
            float wh0 = ((unsigned)ih       < (unsigned)S_) ? 1.f - fh : 0.f;
            float wh1 = ((unsigned)(ih + 1) < (unsigned)S_) ? fh       : 0.f;
            float ww0 = ((unsigned)iw       < (unsigned)S_) ? 1.f - fw : 0.f;
            float ww1 = ((unsigned)(iw + 1) < (unsigned)S_) ? fw       : 0.f;
            unsigned short* p = &sw[idx * 12];
            p[0] = f2bf(wd0 * wh0); p[1] = f2bf(wd0 * wh1);
            p[2] = f2bf(wd1 * wh0); p[3] = f2bf(wd1 * wh1);
            p[4] = f2bf(ww0);       p[5] = f2bf(ww1);
            p[6] = (unsigned short)(d0 * 400 + h0 * 20);
            p[7] = (unsigned short)(d0 * 400 + h1 * 20);
            p[8] = (unsigned short)(d1 * 400 + h0 * 20);
            p[9] = (unsigned short)(d1 * 400 + h1 * 20);
            p[10] = (unsigned short)w0; p[11] = (unsigned short)w1;
        }
    }
    __syncthreads();

    const int c = tid & 31;
    const int vl = tid >> 5;
    const int v = Vb + vl;
    const unsigned short* xc = xtb + c;
    float acc = 0.f;
    #pragma unroll 2
    for (int tap = 0; tap < K3_; ++tap) {
        const unsigned* pu = (const unsigned*)&sw[(vl * 128 + tap) * 12];
        unsigned u0 = pu[0], u1 = pu[1], u2 = pu[2];
        unsigned u3 = pu[3], u4 = pu[4], u5 = pu[5];
        float wdh00 = asf(u0 << 16), wdh01 = asf(u0 & 0xFFFF0000u);
        float wdh10 = asf(u1 << 16), wdh11 = asf(u1 & 0xFFFF0000u);
        float ww0   = asf(u2 << 16), ww1   = asf(u2 & 0xFFFF0000u);
        int r00 = u3 & 0xFFFFu, r01 = u3 >> 16;
        int r10 = u4 & 0xFFFFu, r11 = u4 >> 16;
        int w0  = u5 & 0xFFFFu, w1  = u5 >> 16;
        float x000 = bf2f(xc[(r00 + w0) * 32]);
        float x001 = bf2f(xc[(r00 + w1) * 32]);
        float x010 = bf2f(xc[(r01 + w0) * 32]);
        float x011 = bf2f(xc[(r01 + w1) * 32]);
        float x100 = bf2f(xc[(r10 + w0) * 32]);
        float x101 = bf2f(xc[(r10 + w1) * 32]);
        float x110 = bf2f(xc[(r11 + w0) * 32]);
        float x111 = bf2f(xc[(r11 + w1) * 32]);
        float s = (x000 * ww0 + x001 * ww1) * wdh00
                + (x010 * ww0 + x011 * ww1) * wdh01
                + (x100 * ww0 + x101 * ww1) * wdh10
                + (x110 * ww0 + x111 * ww1) * wdh11;
        acc += wdwT[tap * 32 + c] * s;
    }
    attn1T[v * 32 + c] = acc + b_dw[c];
}

// ---------------------------------------------------------------------------
// Depthwise 7^3 conv, dilation 3, pad 9, channel-last, coalesced.
// ---------------------------------------------------------------------------
__global__ __launch_bounds__(256) void spatial_kernel(
    const float* __restrict__ wspT,
    const float* __restrict__ b_sp,
    const float* __restrict__ attn1T,
    float* __restrict__ attn2T)
{
    int t = threadIdx.x;
    int c = t & 31;
    int v = blockIdx.x * 8 + (t >> 5);
    int z = v / 400, rm = v % 400;
    int y = rm / 20, xx = rm % 20;

    float acc = 0.f;
    #pragma unroll 1
    for (int kz = 0; kz < 7; ++kz) {
        int zi = z - 9 + 3 * kz;
        bool zv = (unsigned)zi < (unsigned)S_;
        int zc2 = min(max(zi, 0), S_ - 1);
        #pragma unroll 1
        for (int ky = 0; ky < 7; ++ky) {
            int yi = y - 9 + 3 * ky;
            bool yv = (unsigned)yi < (unsigned)S_;
            int yc2 = min(max(yi, 0), S_ - 1);
            int abase = (zc2 * 400 + yc2 * 20) * 32 + c;
            int wbase = (kz * 49 + ky * 7) * 32 + c;
            #pragma unroll
            for (int kx = 0; kx < 7; ++kx) {
                int xi = xx - 9 + 3 * kx;
                bool xv = (unsigned)xi < (unsigned)S_;
                int xc2 = min(max(xi, 0), S_ - 1);
                float a = attn1T[abase + xc2 * 32];
                float w = wspT[wbase + kx * 32];
                acc += (zv && yv && xv) ? a * w : 0.f;
            }
        }
    }
    attn2T[v * 32 + c] = acc + b_sp[c];
}

// ---------------------------------------------------------------------------
// Pointwise 32x32 + bias, gate: out[o][v] = x[o][v] * attn.
// ---------------------------------------------------------------------------
__global__ __launch_bounds__(256) void pw_kernel(
    const float* __restrict__ x,
    const float* __restrict__ wpwT,
    const float* __restrict__ b_pw,
    const float* __restrict__ attn2T,
    float* __restrict__ out)
{
    int t = threadIdx.x;
    int o = t & 31;
    int v = blockIdx.x * 8 + (t >> 5);
    float acc = b_pw[o];
    #pragma unroll
    for (int c = 0; c < C_; ++c)
        acc += wpwT[c * 32 + o] * attn2T[v * 32 + c];
    out[o * V_ + v] = x[o * V_ + v] * acc;
}

// ---------------------------------------------------------------------------
extern "C" void kernel_launch(void* const* d_in, const int* in_sizes, int n_in,
                              void* d_out, int out_size, void* d_ws, size_t ws_size,
                              hipStream_t stream)
{
    const float* x     = (const float*)d_in[0];
    const float* w_off = (const float*)d_in[1];
    const float* b_off = (const float*)d_in[2];
    const float* w_dw  = (const float*)d_in[3];
    const float* b_dw  = (const float*)d_in[4];
    const float* w_sp  = (const float*)d_in[5];
    const float* b_sp  = (const float*)d_in[6];
    const float* w_pw  = (const float*)d_in[7];
    const float* b_pw  = (const float*)d_in[8];
    float* ws = (float*)d_ws;
    float* out = (float*)d_out;

    unsigned short* xtb   = (unsigned short*)(ws + WS_XTB);
    unsigned short* offbT = (unsigned short*)(ws + WS_OFFB);
    unsigned short* Bprep = (unsigned short*)(ws + WS_BPREP);

    hipLaunchKernelGGL(transpose_kernel, dim3((272000 + 255) / 256), dim3(256), 0, stream,
                       x, w_dw, w_sp, w_pw, xtb,
                       ws + WS_WDWT, ws + WS_WSPT, ws + WS_WPWT);

    hipLaunchKernelGGL(prep_b_kernel, dim3((NP_ * KK_ + 255) / 256), dim3(256), 0, stream,
                       w_off, Bprep);

    hipLaunchKernelGGL(gemm_off_kernel, dim3(125, 6), dim3(256), 0, stream,
                       xtb, Bprep, b_off, offbT);

    hipLaunchKernelGGL(deform_kernel, dim3(1000), dim3(256), 0, stream,
                       xtb, ws + WS_WDWT, b_dw, offbT, ws + WS_ATTN1T);

    hipLaunchKernelGGL(spatial_kernel, dim3(1000), dim3(256), 0, stream,
                       ws + WS_WSPT, b_sp, ws + WS_ATTN1T, ws + WS_ATTN2T);

    hipLaunchKernelGGL(pw_kernel, dim3(1000), dim3(256), 0, stream,
                       x, ws + WS_WPWT, b_pw, ws + WS_ATTN2T, out);
}